// Round 2
// baseline (3633.908 us; speedup 1.0000x reference)
//
#include <hip/hip_runtime.h>
#include <hip/hip_bf16.h>
#include <math.h>

typedef short bf16x8 __attribute__((ext_vector_type(8)));
typedef float f32x4 __attribute__((ext_vector_type(4)));
using bf16_t = __hip_bfloat16;

#define DEV static __device__ __forceinline__

DEV unsigned short f2bu(float x) {
  bf16_t h = __float2bfloat16(x);
  unsigned short u;
  __builtin_memcpy(&u, &h, 2);
  return u;
}
DEV void st4(bf16_t* p, float a, float b, float c, float d) {
  ushort4 u;
  u.x = f2bu(a); u.y = f2bu(b); u.z = f2bu(c); u.w = f2bu(d);
  *reinterpret_cast<ushort4*>(p) = u;
}

// ---------------- weight transpose + bf16 convert: W[in][out] -> WT[out][in] ----------------
__global__ __launch_bounds__(256) void k_wt(const float* __restrict__ W, bf16_t* __restrict__ WT,
                                            int in_dim, int out_dim) {
  __shared__ float tile[32][33];
  int i0 = blockIdx.x * 32;
  int o0 = blockIdx.y * 32;
  int tx = threadIdx.x & 31, ty = threadIdx.x >> 5;
  for (int r = ty; r < 32; r += 8)
    tile[r][tx] = W[(size_t)(i0 + r) * out_dim + (o0 + tx)];
  __syncthreads();
  for (int r = ty; r < 32; r += 8)
    WT[(size_t)(o0 + r) * in_dim + (i0 + tx)] = __float2bfloat16(tile[tx][r]);
}

// ---------------- stage-1 elementwise prep (full tensor) ----------------
__global__ __launch_bounds__(256) void k_prep1(const float4* __restrict__ q, const float4* __restrict__ ce,
                                               const float4* __restrict__ pe, float4* __restrict__ q0,
                                               bf16_t* __restrict__ qpe_b, bf16_t* __restrict__ q0_b, int n4) {
  int i = blockIdx.x * 256 + threadIdx.x;
  if (i >= n4) return;
  float4 a = q[i], b = ce[i], p = pe[i];
  float4 s; s.x = a.x + b.x; s.y = a.y + b.y; s.z = a.z + b.z; s.w = a.w + b.w;
  q0[i] = s;
  st4(q0_b + 4 * (size_t)i, s.x, s.y, s.z, s.w);
  st4(qpe_b + 4 * (size_t)i, s.x + p.x, s.y + p.y, s.z + p.z, s.w + p.w);
}

// ---------------- build K2/V2/Qf for cross-attn 2, single batch b ----------------
__global__ __launch_bounds__(256) void k_build2b(const float* __restrict__ q1,
    const float* __restrict__ imA, const float* __restrict__ imB, const float* __restrict__ pe,
    const float* __restrict__ fa, const float* __restrict__ fb, const float* __restrict__ fc,
    bf16_t* __restrict__ k2, bf16_t* __restrict__ v2, bf16_t* __restrict__ qf, int b) {
  int idx = blockIdx.x * 256 + threadIdx.x;     // over 3N*(C/4)
  int c4 = idx % 192; int rem = idx / 192;      // rem < 3072
  int seg = rem >> 10; int n = rem & 1023;
  int c = c4 * 4;
  size_t tok = (size_t)(b * 1024 + n) * 768 + c;
  float4 p = *(const float4*)(pe + tok);
  const float* srcp; const float* flg;
  if (seg == 0)      { srcp = imA + tok; flg = fa; }
  else if (seg == 1) { srcp = imB + tok; flg = fb; }
  else               { srcp = q1 + tok; flg = fc; }
  float4 s = *(const float4*)srcp;
  float4 f = *(const float4*)(flg + c);
  size_t o = (size_t)idx * 4;
  st4(v2 + o, s.x, s.y, s.z, s.w);
  float kx = s.x + p.x + f.x, ky = s.y + p.y + f.y, kz = s.z + p.z + f.z, kw = s.w + p.w + f.w;
  st4(k2 + o, kx, ky, kz, kw);
  if (seg == 2) st4(qf + (size_t)n * 768 + c, kx, ky, kz, kw);
}

// ---------------- build K3/V3/QQ for cross-attn 3, single "bb" (0..7) ----------------
__global__ __launch_bounds__(256) void k_build3b(const float* __restrict__ q3,
    const float* __restrict__ imA, const float* __restrict__ imB, const float* __restrict__ pe,
    const float* __restrict__ fa, const float* __restrict__ fb, const float* __restrict__ fc,
    bf16_t* __restrict__ k3, bf16_t* __restrict__ v3, bf16_t* __restrict__ qq, int bb) {
  int idx = blockIdx.x * 256 + threadIdx.x;     // over 2N*(C/4)
  int c4 = idx % 192; int rem = idx / 192;      // rem < 2048
  int seg = rem >> 10; int n = rem & 1023;
  int b = bb & 3; int isB = bb >> 2;
  int c = c4 * 4;
  size_t tok = (size_t)(b * 1024 + n) * 768 + c;
  float4 p = *(const float4*)(pe + tok);
  const float* srcp; const float* flg;
  if (seg == 0) { srcp = (isB ? imB : imA) + tok; flg = isB ? fb : fa; }
  else          { srcp = q3 + tok; flg = fc; }
  float4 s = *(const float4*)srcp;
  float4 f = *(const float4*)(flg + c);
  size_t o = (size_t)idx * 4;
  st4(v3 + o, s.x, s.y, s.z, s.w);
  float kx = s.x + p.x + f.x, ky = s.y + p.y + f.y, kz = s.z + p.z + f.z, kw = s.w + p.w + f.w;
  st4(k3 + o, kx, ky, kz, kw);
  if (seg == 0) st4(qq + (size_t)n * 768 + c, kx, ky, kz, kw);
}

// ---------------- V transpose: [Nk,H,D] -> [H,D,Nk] (single batch; grid.z = H) ----------------
__global__ __launch_bounds__(256) void k_vt(const bf16_t* __restrict__ V, bf16_t* __restrict__ vT,
                                            int Nk, int C) {
  int h = blockIdx.z;
  int n0 = blockIdx.x * 32, d0 = blockIdx.y * 32;
  __shared__ bf16_t t[32][33];
  const bf16_t* src = V + h * 128;
  int tx = threadIdx.x & 31, ty = threadIdx.x >> 5;
  for (int r = ty; r < 32; r += 8) t[r][tx] = src[(size_t)(n0 + r) * C + d0 + tx];
  __syncthreads();
  for (int r = ty; r < 32; r += 8)
    vT[((size_t)h * 128 + d0 + r) * Nk + n0 + tx] = t[tx][r];
}

// ---------------- row softmax (in-place, bf16) ----------------
__global__ __launch_bounds__(256) void k_softmax(bf16_t* __restrict__ S, int Nk) {
  __shared__ float buf[3072];
  __shared__ float red[8];
  bf16_t* row = S + (size_t)blockIdx.x * Nk;
  int tid = threadIdx.x;
  float mx = -3.0e38f;
  for (int c = tid; c < Nk; c += 256) {
    float v = __bfloat162float(row[c]);
    buf[c] = v;
    mx = fmaxf(mx, v);
  }
  for (int o = 32; o; o >>= 1) mx = fmaxf(mx, __shfl_xor(mx, o));
  if ((tid & 63) == 0) red[tid >> 6] = mx;
  __syncthreads();
  mx = fmaxf(fmaxf(red[0], red[1]), fmaxf(red[2], red[3]));
  float sum = 0.f;
  for (int c = tid; c < Nk; c += 256) {
    float e = __expf(buf[c] - mx);
    buf[c] = e;
    sum += e;
  }
  for (int o = 32; o; o >>= 1) sum += __shfl_xor(sum, o);
  if ((tid & 63) == 0) red[4 + (tid >> 6)] = sum;
  __syncthreads();
  sum = red[4] + red[5] + red[6] + red[7];
  float inv = 1.0f / sum;
  for (int c = tid; c < Nk; c += 256) row[c] = __float2bfloat16(buf[c] * inv);
}

// ---------------- fused residual + LayerNorm; X/outputs full-tensor, A local (row0-based) ----------------
__global__ __launch_bounds__(256) void k_ln(const float* __restrict__ X, const float* __restrict__ A,
                                            const float* __restrict__ w, const float* __restrict__ bvec,
                                            float* __restrict__ outf, bf16_t* __restrict__ outb, int row0) {
  int row = blockIdx.x, tid = threadIdx.x;
  const float* x = X + (size_t)(row0 + row) * 768;
  const float* a = A + (size_t)row * 768;
  float v0 = x[tid] + a[tid];
  float v1 = x[tid + 256] + a[tid + 256];
  float v2 = x[tid + 512] + a[tid + 512];
  float s = v0 + v1 + v2;
  for (int o = 32; o; o >>= 1) s += __shfl_xor(s, o);
  __shared__ float sm[8];
  int wv = tid >> 6, ln = tid & 63;
  if (ln == 0) sm[wv] = s;
  __syncthreads();
  s = sm[0] + sm[1] + sm[2] + sm[3];
  float mean = s * (1.0f / 768.0f);
  float d0 = v0 - mean, d1 = v1 - mean, d2 = v2 - mean;
  float ss = d0 * d0 + d1 * d1 + d2 * d2;
  for (int o = 32; o; o >>= 1) ss += __shfl_xor(ss, o);
  if (ln == 0) sm[4 + wv] = ss;
  __syncthreads();
  ss = sm[4] + sm[5] + sm[6] + sm[7];
  float rstd = rsqrtf(ss * (1.0f / 768.0f) + 1e-5f);
  float o0 = d0 * rstd * w[tid] + bvec[tid];
  float o1 = d1 * rstd * w[tid + 256] + bvec[tid + 256];
  float o2 = d2 * rstd * w[tid + 512] + bvec[tid + 512];
  size_t base = (size_t)(row0 + row) * 768;
  outf[base + tid] = o0; outf[base + tid + 256] = o1; outf[base + tid + 512] = o2;
  if (outb) {
    outb[base + tid] = __float2bfloat16(o0);
    outb[base + tid + 256] = __float2bfloat16(o1);
    outb[base + tid + 512] = __float2bfloat16(o2);
  }
}

// ---------------- stage-3 final: out = (img + pe + flag) + a4_b, single bb ----------------
__global__ __launch_bounds__(256) void k_out3(const float* __restrict__ imA, const float* __restrict__ imB,
                                              const float* __restrict__ pe, const float* __restrict__ fa,
                                              const float* __restrict__ fb, const float* __restrict__ a4,
                                              float* __restrict__ out, int bb) {
  int idx = blockIdx.x * 256 + threadIdx.x;     // over N*C/4
  int c4 = idx % 192; int n = idx / 192;
  int c = c4 * 4;
  int b = bb & 3, isB = bb >> 2;
  size_t tok = (size_t)(b * 1024 + n) * 768 + c;
  const float* src = isB ? imB : imA;
  const float* flg = isB ? fb : fa;
  float4 sv = *(const float4*)(src + tok);
  float4 p = *(const float4*)(pe + tok);
  float4 f = *(const float4*)(flg + c);
  float4 a = *(const float4*)(a4 + (size_t)n * 768 + c);
  float4 r;
  r.x = sv.x + p.x + f.x + a.x;
  r.y = sv.y + p.y + f.y + a.y;
  r.z = sv.z + p.z + f.z + a.z;
  r.w = sv.w + p.w + f.w + a.w;
  *(float4*)(out + (size_t)(bb * 1024 + n) * 768 + c) = r;
}

// ---------------- bf16 MFMA GEMM: Out = alpha*(X @ Wt^T) + bias, optional GELU ----------------
template<int OUTBF, int GELU>
__global__ __launch_bounds__(256, 2) void k_gemm(
    const bf16_t* __restrict__ X, const bf16_t* __restrict__ Wt,
    const float* __restrict__ bias, void* __restrict__ Out,
    int M, int Nout, int K, int ldx, int ldw, int ldo, float alpha,
    int HDIV, long sxb, long sxh, long swb, long swh, long sob, long soh) {
  int z = blockIdx.z;
  int zb = z / HDIV, zh = z % HDIV;
  X  += (size_t)zb * sxb + (size_t)zh * sxh;
  Wt += (size_t)zb * swb + (size_t)zh * swh;
  size_t outOff = (size_t)zb * sob + (size_t)zh * soh;

  const int brow = blockIdx.y * 128;
  const int bcol = blockIdx.x * 128;

  __shared__ bf16_t As[128][40];
  __shared__ bf16_t Bs[128][40];

  const int tid = threadIdx.x;
  const int lane = tid & 63;
  const int wave = tid >> 6;
  const int wr = wave >> 1;
  const int wc = wave & 1;

  f32x4 acc[4][4];
#pragma unroll
  for (int i = 0; i < 4; i++)
#pragma unroll
    for (int j = 0; j < 4; j++) {
      f32x4 zz = {0.f, 0.f, 0.f, 0.f};
      acc[i][j] = zz;
    }

  const int sr0 = tid >> 2;
  const int sc0 = (tid & 3) * 8;

  const int nK = K >> 5;
  for (int kk = 0; kk < nK; ++kk) {
    const int k0 = kk << 5;
    uint4 v0 = *reinterpret_cast<const uint4*>(X + (size_t)(brow + sr0) * ldx + k0 + sc0);
    uint4 v1 = *reinterpret_cast<const uint4*>(X + (size_t)(brow + 64 + sr0) * ldx + k0 + sc0);
    uint4 w0 = *reinterpret_cast<const uint4*>(Wt + (size_t)(bcol + sr0) * ldw + k0 + sc0);
    uint4 w1 = *reinterpret_cast<const uint4*>(Wt + (size_t)(bcol + 64 + sr0) * ldw + k0 + sc0);
    __syncthreads();
    *reinterpret_cast<uint4*>(&As[sr0][sc0]) = v0;
    *reinterpret_cast<uint4*>(&As[64 + sr0][sc0]) = v1;
    *reinterpret_cast<uint4*>(&Bs[sr0][sc0]) = w0;
    *reinterpret_cast<uint4*>(&Bs[64 + sr0][sc0]) = w1;
    __syncthreads();

    bf16x8 afr[4], bfr[4];
    const int lrow = lane & 15;
    const int kch = (lane >> 4) * 8;
#pragma unroll
    for (int i = 0; i < 4; i++)
      afr[i] = *reinterpret_cast<const bf16x8*>(&As[wr * 64 + i * 16 + lrow][kch]);
#pragma unroll
    for (int j = 0; j < 4; j++)
      bfr[j] = *reinterpret_cast<const bf16x8*>(&Bs[wc * 64 + j * 16 + lrow][kch]);
#pragma unroll
    for (int i = 0; i < 4; i++)
#pragma unroll
      for (int j = 0; j < 4; j++)
        acc[i][j] = __builtin_amdgcn_mfma_f32_16x16x32_bf16(afr[i], bfr[j], acc[i][j], 0, 0, 0);
  }

  const int lcol = lane & 15;
  const int lrow4 = (lane >> 4) * 4;
#pragma unroll
  for (int i = 0; i < 4; i++) {
    int row0 = brow + wr * 64 + i * 16 + lrow4;
#pragma unroll
    for (int j = 0; j < 4; j++) {
      int col = bcol + wc * 64 + j * 16 + lcol;
      float bv = bias ? bias[col] : 0.0f;
#pragma unroll
      for (int r = 0; r < 4; r++) {
        float v = acc[i][j][r] * alpha + bv;
        if (GELU) v = 0.5f * v * (1.0f + erff(v * 0.70710678118f));
        size_t idx = outOff + (size_t)(row0 + r) * ldo + col;
        if (OUTBF) reinterpret_cast<bf16_t*>(Out)[idx] = __float2bfloat16(v);
        else reinterpret_cast<float*>(Out)[idx] = v;
      }
    }
  }
}

static inline void gemm(hipStream_t st, const bf16_t* X, const bf16_t* Wt, const float* bias,
                        void* out, int outBf, int gelu,
                        int M, int N, int K, int ldx, int ldw, int ldo, float alpha,
                        int nz = 1, int hdiv = 1,
                        long sxb = 0, long sxh = 0, long swb = 0, long swh = 0,
                        long sob = 0, long soh = 0) {
  dim3 g(N / 128, M / 128, nz), blk(256);
  if (outBf) {
    if (gelu) k_gemm<1, 1><<<g, blk, 0, st>>>(X, Wt, bias, out, M, N, K, ldx, ldw, ldo, alpha, hdiv, sxb, sxh, swb, swh, sob, soh);
    else      k_gemm<1, 0><<<g, blk, 0, st>>>(X, Wt, bias, out, M, N, K, ldx, ldw, ldo, alpha, hdiv, sxb, sxh, swb, swh, sob, soh);
  } else      k_gemm<0, 0><<<g, blk, 0, st>>>(X, Wt, bias, out, M, N, K, ldx, ldw, ldo, alpha, hdiv, sxb, sxh, swb, swh, sob, soh);
}

extern "C" void kernel_launch(void* const* d_in, const int* in_sizes, int n_in,
                              void* d_out, int out_size, void* d_ws, size_t ws_size,
                              hipStream_t stream) {
  (void)in_sizes; (void)n_in; (void)out_size; (void)ws_size;
  constexpr int B = 4, N = 1024, C = 768, Hh = 6, Dd = 128, MLPD = 2304;
  constexpr size_t BNC = (size_t)B * N * C;
  constexpr size_t NC  = (size_t)N * C;
  const float scale = 0.08838834764831845f;   // 1/sqrt(128)

  const float* queries = (const float*)d_in[0];
  const float* change  = (const float*)d_in[1];
  const float* imA     = (const float*)d_in[2];
  const float* imB     = (const float*)d_in[3];
  const float* pe      = (const float*)d_in[4];
  const float* bq1 = (const float*)d_in[6];  const float* bk1 = (const float*)d_in[8];
  const float* bv1 = (const float*)d_in[10]; const float* bo1 = (const float*)d_in[12];
  const float* bq2 = (const float*)d_in[14]; const float* bk2 = (const float*)d_in[16];
  const float* bv2 = (const float*)d_in[18]; const float* bo2 = (const float*)d_in[20];
  const float* bq3 = (const float*)d_in[22]; const float* bk3 = (const float*)d_in[24];
  const float* bv3 = (const float*)d_in[26]; const float* bo3 = (const float*)d_in[28];
  const float* ln1w = (const float*)d_in[29]; const float* ln1b = (const float*)d_in[30];
  const float* ln2w = (const float*)d_in[31]; const float* ln2b = (const float*)d_in[32];
  const float* ln3w = (const float*)d_in[33]; const float* ln3b = (const float*)d_in[34];
  const float* mb1 = (const float*)d_in[36]; const float* mb2 = (const float*)d_in[38];
  const float* fa = (const float*)d_in[39];
  const float* fb = (const float*)d_in[40];
  const float* fc = (const float*)d_in[41];

  char* base = (char*)d_ws;
  size_t off = 0;
  auto alloc = [&](size_t bytes) -> void* {
    void* p = base + off;
    off += (bytes + 255) & ~(size_t)255;
    return p;
  };

  // ---- persistent: bf16 weights + residual activations live across stages ----
  bf16_t* WT[14];
  const int widx[14] = {5, 7, 9, 11, 13, 15, 17, 19, 21, 23, 25, 27, 35, 37};
  const int wins[14] = {768, 768, 768, 768, 768, 768, 768, 768, 768, 768, 768, 768, 768, 2304};
  const int wout[14] = {768, 768, 768, 768, 768, 768, 768, 768, 768, 768, 768, 768, 2304, 768};
  for (int i = 0; i < 14; i++) WT[i] = (bf16_t*)alloc((size_t)wins[i] * wout[i] * 2);
  float*  q1  = (float*)alloc(BNC * 4);
  float*  q2  = (float*)alloc(BNC * 4);
  bf16_t* q2b = (bf16_t*)alloc(BNC * 2);
  const size_t arena = off;   // ~52.7 MB persistent; stage scratch reuses beyond this

  for (int i = 0; i < 14; i++) {
    dim3 g(wins[i] / 32, wout[i] / 32);
    k_wt<<<g, 256, 0, stream>>>((const float*)d_in[widx[i]], WT[i], wins[i], wout[i]);
  }

  // ================= stage 1: self-attention (per-batch) =================
  off = arena;
  float*  q0    = (float*)alloc(BNC * 4);
  bf16_t* qpe_b = (bf16_t*)alloc(BNC * 2);
  bf16_t* q0_b  = (bf16_t*)alloc(BNC * 2);
  bf16_t* Qh_b  = (bf16_t*)alloc(NC * 2);
  bf16_t* Kh_b  = (bf16_t*)alloc(NC * 2);
  bf16_t* Vh_b  = (bf16_t*)alloc(NC * 2);
  bf16_t* vT_b  = (bf16_t*)alloc(NC * 2);
  bf16_t* attC_b = (bf16_t*)alloc(NC * 2);
  float*  a1_b  = (float*)alloc(NC * 4);
  bf16_t* sc1_b = (bf16_t*)alloc((size_t)Hh * N * N * 2);

  k_prep1<<<dim3((int)(BNC / 4 / 256)), 256, 0, stream>>>(
      (const float4*)queries, (const float4*)change, (const float4*)pe,
      (float4*)q0, qpe_b, q0_b, (int)(BNC / 4));

  for (int b = 0; b < B; ++b) {
    gemm(stream, qpe_b + (size_t)b * NC, WT[0], bq1, Qh_b, 1, 0, N, C, C, C, C, C, 1.0f);
    gemm(stream, qpe_b + (size_t)b * NC, WT[1], bk1, Kh_b, 1, 0, N, C, C, C, C, C, 1.0f);
    gemm(stream, q0_b  + (size_t)b * NC, WT[2], bv1, Vh_b, 1, 0, N, C, C, C, C, C, 1.0f);
    k_vt<<<dim3(N / 32, 4, Hh), 256, 0, stream>>>(Vh_b, vT_b, N, C);
    gemm(stream, Qh_b, Kh_b, nullptr, sc1_b, 1, 0, N, N, Dd, C, C, N, scale,
         Hh, Hh, 0, 128, 0, 128, 0, (long)N * N);
    k_softmax<<<dim3(Hh * N), 256, 0, stream>>>(sc1_b, N);
    gemm(stream, sc1_b, vT_b, nullptr, attC_b, 1, 0, N, Dd, N, N, N, C, 1.0f,
         Hh, Hh, 0, (long)N * N, 0, (long)Dd * N, 0, 128);
    gemm(stream, attC_b, WT[3], bo1, a1_b, 0, 0, N, C, C, C, C, C, 1.0f);
    k_ln<<<dim3(N), 256, 0, stream>>>(q0, a1_b, ln1w, ln1b, q1, (bf16_t*)nullptr, b * N);
  }

  // ================= stage 2: cross-attn change -> [A,B,change] (per-batch) =================
  off = arena;
  bf16_t* qf_b   = (bf16_t*)alloc(NC * 2);
  bf16_t* k2in_b = (bf16_t*)alloc(3 * NC * 2);
  bf16_t* v2in_b = (bf16_t*)alloc(3 * NC * 2);
  bf16_t* Q2h_b  = (bf16_t*)alloc(NC * 2);
  bf16_t* K2h_b  = (bf16_t*)alloc(3 * NC * 2);
  bf16_t* V2h_b  = (bf16_t*)alloc(3 * NC * 2);
  bf16_t* vT2_b  = (bf16_t*)alloc(3 * NC * 2);
  bf16_t* attC2_b = (bf16_t*)alloc(NC * 2);
  float*  a2_b   = (float*)alloc(NC * 4);
  bf16_t* sc2_b  = (bf16_t*)alloc((size_t)3 * N * (3 * N) * 2);

  for (int b = 0; b < B; ++b) {
    const int Nk = 3 * N;
    k_build2b<<<dim3((int)(3 * NC / 4 / 256)), 256, 0, stream>>>(
        q1, imA, imB, pe, fa, fb, fc, k2in_b, v2in_b, qf_b, b);
    gemm(stream, qf_b,   WT[4], bq2, Q2h_b, 1, 0, N, C, C, C, C, C, 1.0f);
    gemm(stream, k2in_b, WT[5], bk2, K2h_b, 1, 0, Nk, C, C, C, C, C, 1.0f);
    gemm(stream, v2in_b, WT[6], bv2, V2h_b, 1, 0, Nk, C, C, C, C, C, 1.0f);
    k_vt<<<dim3(Nk / 32, 4, Hh), 256, 0, stream>>>(V2h_b, vT2_b, Nk, C);
    for (int hp = 0; hp < 2; ++hp) {            // 3 heads per slice
      gemm(stream, Q2h_b + hp * 384, K2h_b + hp * 384, nullptr, sc2_b, 1, 0,
           N, Nk, Dd, C, C, Nk, scale, 3, 3, 0, 128, 0, 128, 0, (long)N * Nk);
      k_softmax<<<dim3(3 * N), 256, 0, stream>>>(sc2_b, Nk);
      gemm(stream, sc2_b, vT2_b + (size_t)hp * 3 * Dd * Nk, nullptr, attC2_b + hp * 384, 1, 0,
           N, Dd, Nk, Nk, Nk, C, 1.0f, 3, 3, 0, (long)N * Nk, 0, (long)Dd * Nk, 0, 128);
    }
    gemm(stream, attC2_b, WT[7], bo2, a2_b, 0, 0, N, C, C, C, C, C, 1.0f);
    k_ln<<<dim3(N), 256, 0, stream>>>(q1, a2_b, ln2w, ln2b, q2, q2b, b * N);
  }

  // ================= MLP =================
  off = arena;
  bf16_t* h1 = (bf16_t*)alloc((size_t)B * N * MLPD * 2);
  float*  a3 = (float*)alloc(BNC * 4);
  gemm(stream, q2b, WT[12], mb1, h1, 1, 1, B * N, MLPD, C, C, C, MLPD, 1.0f);
  gemm(stream, h1, WT[13], mb2, a3, 0, 0, B * N, C, MLPD, MLPD, MLPD, C, 1.0f);
  float* chg = (float*)d_out + 2 * BNC;
  k_ln<<<dim3(B * N), 256, 0, stream>>>(q2, a3, ln3w, ln3b, chg, (bf16_t*)nullptr, 0);

  // ================= stage 3: [A;B] -> [image;change] (per-bb) =================
  off = arena;
  bf16_t* qq_b   = (bf16_t*)alloc(NC * 2);
  bf16_t* k3in_b = (bf16_t*)alloc(2 * NC * 2);
  bf16_t* v3in_b = (bf16_t*)alloc(2 * NC * 2);
  bf16_t* Q3h_b  = (bf16_t*)alloc(NC * 2);
  bf16_t* K3h_b  = (bf16_t*)alloc(2 * NC * 2);
  bf16_t* V3h_b  = (bf16_t*)alloc(2 * NC * 2);
  bf16_t* vT3_b  = (bf16_t*)alloc(2 * NC * 2);
  bf16_t* attC3_b = (bf16_t*)alloc(NC * 2);
  float*  a4_b   = (float*)alloc(NC * 4);
  bf16_t* sc3_b  = (bf16_t*)alloc((size_t)3 * N * (2 * N) * 2);

  for (int bb = 0; bb < 2 * B; ++bb) {
    const int Nk = 2 * N;
    k_build3b<<<dim3((int)(2 * NC / 4 / 256)), 256, 0, stream>>>(
        chg, imA, imB, pe, fa, fb, fc, k3in_b, v3in_b, qq_b, bb);
    gemm(stream, qq_b,   WT[8],  bq3, Q3h_b, 1, 0, N, C, C, C, C, C, 1.0f);
    gemm(stream, k3in_b, WT[9],  bk3, K3h_b, 1, 0, Nk, C, C, C, C, C, 1.0f);
    gemm(stream, v3in_b, WT[10], bv3, V3h_b, 1, 0, Nk, C, C, C, C, C, 1.0f);
    k_vt<<<dim3(Nk / 32, 4, Hh), 256, 0, stream>>>(V3h_b, vT3_b, Nk, C);
    for (int hp = 0; hp < 2; ++hp) {
      gemm(stream, Q3h_b + hp * 384, K3h_b + hp * 384, nullptr, sc3_b, 1, 0,
           N, Nk, Dd, C, C, Nk, scale, 3, 3, 0, 128, 0, 128, 0, (long)N * Nk);
      k_softmax<<<dim3(3 * N), 256, 0, stream>>>(sc3_b, Nk);
      gemm(stream, sc3_b, vT3_b + (size_t)hp * 3 * Dd * Nk, nullptr, attC3_b + hp * 384, 1, 0,
           N, Dd, Nk, Nk, Nk, C, 1.0f, 3, 3, 0, (long)N * Nk, 0, (long)Dd * Nk, 0, 128);
    }
    gemm(stream, attC3_b, WT[11], bo3, a4_b, 0, 0, N, C, C, C, C, C, 1.0f);
    k_out3<<<dim3((int)(NC / 4 / 256)), 256, 0, stream>>>(imA, imB, pe, fa, fb, a4_b,
                                                          (float*)d_out, bb);
  }
}

// Round 3
// 2278.972 us; speedup vs baseline: 1.5945x; 1.5945x over previous
//
#include <hip/hip_runtime.h>
#include <hip/hip_bf16.h>
#include <math.h>

typedef short bf16x8 __attribute__((ext_vector_type(8)));
typedef float f32x4 __attribute__((ext_vector_type(4)));
using bf16_t = __hip_bfloat16;

#define DEV static __device__ __forceinline__

DEV unsigned short f2bu(float x) {
  bf16_t h = __float2bfloat16(x);
  unsigned short u;
  __builtin_memcpy(&u, &h, 2);
  return u;
}
DEV void st4(bf16_t* p, float a, float b, float c, float d) {
  ushort4 u;
  u.x = f2bu(a); u.y = f2bu(b); u.z = f2bu(c); u.w = f2bu(d);
  *reinterpret_cast<ushort4*>(p) = u;
}

// ---------------- weight transpose + bf16 convert: W[in][out] -> WT[out][in] ----------------
__global__ __launch_bounds__(256) void k_wt(const float* __restrict__ W, bf16_t* __restrict__ WT,
                                            int in_dim, int out_dim) {
  __shared__ float tile[32][33];
  int i0 = blockIdx.x * 32;
  int o0 = blockIdx.y * 32;
  int tx = threadIdx.x & 31, ty = threadIdx.x >> 5;
  for (int r = ty; r < 32; r += 8)
    tile[r][tx] = W[(size_t)(i0 + r) * out_dim + (o0 + tx)];
  __syncthreads();
  for (int r = ty; r < 32; r += 8)
    WT[(size_t)(o0 + r) * in_dim + (i0 + tx)] = __float2bfloat16(tile[tx][r]);
}

// ---------------- stage-1 elementwise prep ----------------
__global__ __launch_bounds__(256) void k_prep1(const float4* __restrict__ q, const float4* __restrict__ ce,
                                               const float4* __restrict__ pe,
                                               bf16_t* __restrict__ qpe_b, bf16_t* __restrict__ q0_b, int n4) {
  int i = blockIdx.x * 256 + threadIdx.x;
  if (i >= n4) return;
  float4 a = q[i], b = ce[i], p = pe[i];
  float sx = a.x + b.x, sy = a.y + b.y, sz = a.z + b.z, sw = a.w + b.w;
  st4(q0_b + 4 * (size_t)i, sx, sy, sz, sw);
  st4(qpe_b + 4 * (size_t)i, sx + p.x, sy + p.y, sz + p.z, sw + p.w);
}

// ---------------- out[row] = x[row] + pe[row] + flag (bf16), rows = B*N ----------------
__global__ __launch_bounds__(256) void k_addpe(const float* __restrict__ x, const float* __restrict__ pe,
                                               const float* __restrict__ flag, bf16_t* __restrict__ out) {
  int idx = blockIdx.x * 256 + threadIdx.x;     // over B*N*(C/4)
  int c = (idx % 192) * 4;
  size_t tok = (size_t)idx * 4;
  float4 xv = *(const float4*)(x + tok);
  float4 p = *(const float4*)(pe + tok);
  float4 f = *(const float4*)(flag + c);
  st4(out + tok, xv.x + p.x + f.x, xv.y + p.y + f.y, xv.z + p.z + f.z, xv.w + p.w + f.w);
}

// ---------------- build qq for cross-attn 3 (rows = 2B*N) ----------------
__global__ __launch_bounds__(256) void k_buildqq(const float* __restrict__ imA, const float* __restrict__ imB,
                                                 const float* __restrict__ pe, const float* __restrict__ fa,
                                                 const float* __restrict__ fb, bf16_t* __restrict__ qq) {
  int idx = blockIdx.x * 256 + threadIdx.x;     // over 2B*N*(C/4)
  int c4 = idx % 192; int rem = idx / 192;
  int n = rem & 1023; int bb = rem >> 10;
  int b = bb & 3, isB = bb >> 2;
  int c = c4 * 4;
  size_t tok = (size_t)(b * 1024 + n) * 768 + c;
  float4 s = *(const float4*)((isB ? imB : imA) + tok);
  float4 p = *(const float4*)(pe + tok);
  float4 f = *(const float4*)((isB ? fb : fa) + c);
  st4(qq + (size_t)rem * 768 + c, s.x + p.x + f.x, s.y + p.y + f.y, s.z + p.z + f.z, s.w + p.w + f.w);
}

// ---------------- build K2/V2 for cross-attn 2, single batch b ----------------
__global__ __launch_bounds__(256) void k_build2b(const float* __restrict__ q1,
    const float* __restrict__ imA, const float* __restrict__ imB, const float* __restrict__ pe,
    const float* __restrict__ fa, const float* __restrict__ fb, const float* __restrict__ fc,
    bf16_t* __restrict__ k2, bf16_t* __restrict__ v2, int b) {
  int idx = blockIdx.x * 256 + threadIdx.x;     // over 3N*(C/4)
  int c4 = idx % 192; int rem = idx / 192;
  int seg = rem >> 10; int n = rem & 1023;
  int c = c4 * 4;
  size_t tok = (size_t)(b * 1024 + n) * 768 + c;
  float4 p = *(const float4*)(pe + tok);
  const float* srcp; const float* flg;
  if (seg == 0)      { srcp = imA + tok; flg = fa; }
  else if (seg == 1) { srcp = imB + tok; flg = fb; }
  else               { srcp = q1 + tok; flg = fc; }
  float4 s = *(const float4*)srcp;
  float4 f = *(const float4*)(flg + c);
  size_t o = (size_t)idx * 4;
  st4(v2 + o, s.x, s.y, s.z, s.w);
  st4(k2 + o, s.x + p.x + f.x, s.y + p.y + f.y, s.z + p.z + f.z, s.w + p.w + f.w);
}

// ---------------- build K3/V3 for cross-attn 3, single "bb" ----------------
__global__ __launch_bounds__(256) void k_build3b(const float* __restrict__ q3,
    const float* __restrict__ imA, const float* __restrict__ imB, const float* __restrict__ pe,
    const float* __restrict__ fa, const float* __restrict__ fb, const float* __restrict__ fc,
    bf16_t* __restrict__ k3, bf16_t* __restrict__ v3, int bb) {
  int idx = blockIdx.x * 256 + threadIdx.x;     // over 2N*(C/4)
  int c4 = idx % 192; int rem = idx / 192;
  int seg = rem >> 10; int n = rem & 1023;
  int b = bb & 3; int isB = bb >> 2;
  int c = c4 * 4;
  size_t tok = (size_t)(b * 1024 + n) * 768 + c;
  float4 p = *(const float4*)(pe + tok);
  const float* srcp; const float* flg;
  if (seg == 0) { srcp = (isB ? imB : imA) + tok; flg = isB ? fb : fa; }
  else          { srcp = q3 + tok; flg = fc; }
  float4 s = *(const float4*)srcp;
  float4 f = *(const float4*)(flg + c);
  size_t o = (size_t)idx * 4;
  st4(v3 + o, s.x, s.y, s.z, s.w);
  st4(k3 + o, s.x + p.x + f.x, s.y + p.y + f.y, s.z + p.z + f.z, s.w + p.w + f.w);
}

// ---------------- V transpose: [B,Nk,H*D] -> [z=(b,h)][D][Nk] ----------------
__global__ __launch_bounds__(256) void k_vt(const bf16_t* __restrict__ V, bf16_t* __restrict__ vT,
                                            int Nk, int C, int H) {
  int z = blockIdx.z; int b = z / H, h = z % H;
  int n0 = blockIdx.x * 32, d0 = blockIdx.y * 32;
  __shared__ bf16_t t[32][33];
  const bf16_t* src = V + (size_t)b * Nk * C + h * 128;
  bf16_t* dst = vT + (size_t)z * 128 * Nk;
  int tx = threadIdx.x & 31, ty = threadIdx.x >> 5;
  for (int r = ty; r < 32; r += 8) t[r][tx] = src[(size_t)(n0 + r) * C + d0 + tx];
  __syncthreads();
  for (int r = ty; r < 32; r += 8)
    dst[(size_t)(d0 + r) * Nk + n0 + tx] = t[tx][r];
}

// ---------------- flash attention: O = softmax(scale * Q K^T) V ----------------
// grid: (Nq/128, nBH). Q/K: [.][C] row-major with per-(b,h) offsets; Vt: [z][128][Nk].
__global__ __launch_bounds__(256, 2) void k_flash(
    const bf16_t* __restrict__ Q, const bf16_t* __restrict__ K,
    const bf16_t* __restrict__ Vt, bf16_t* __restrict__ O,
    int Nk, int C, int H, float scale, long qStrideB, long kStrideB) {
  const int z = blockIdx.y; const int b = z / H, h = z % H;
  const bf16_t* Qb = Q + (size_t)b * qStrideB + h * 128;
  const bf16_t* Kb = K + (size_t)b * kStrideB + h * 128;
  const bf16_t* Vb = Vt + (size_t)z * 128 * Nk;
  bf16_t* Ob = O + (size_t)b * qStrideB + h * 128;
  const int q0 = blockIdx.x * 128;
  const int tid = threadIdx.x, lane = tid & 63, w = tid >> 6;
  const int g = lane >> 4, c = lane & 15;

  __shared__ bf16_t Ks[64][136];
  __shared__ bf16_t Vs[128][72];
  __shared__ bf16_t Ps[128][72];

  bf16x8 qf[2][4];
#pragma unroll
  for (int i = 0; i < 2; i++)
#pragma unroll
    for (int kk = 0; kk < 4; kk++)
      qf[i][kk] = *reinterpret_cast<const bf16x8*>(
          &Qb[(size_t)(q0 + w * 32 + i * 16 + c) * C + kk * 32 + g * 8]);

  f32x4 oa[2][8];
  float m[2][4], l[2][4];
#pragma unroll
  for (int i = 0; i < 2; i++) {
#pragma unroll
    for (int d = 0; d < 8; d++) { f32x4 zz = {0.f, 0.f, 0.f, 0.f}; oa[i][d] = zz; }
#pragma unroll
    for (int r = 0; r < 4; r++) { m[i][r] = -1.0e30f; l[i][r] = 0.f; }
  }

  const int nt = Nk >> 6;
  for (int t = 0; t < nt; ++t) {
    const int k0 = t << 6;
#pragma unroll
    for (int p = 0; p < 4; p++) {
      int idx = p * 256 + tid;
      int r = idx >> 4, c8 = (idx & 15) * 8;
      *reinterpret_cast<uint4*>(&Ks[r][c8]) =
          *reinterpret_cast<const uint4*>(&Kb[(size_t)(k0 + r) * C + c8]);
    }
#pragma unroll
    for (int p = 0; p < 4; p++) {
      int idx = p * 256 + tid;
      int r = idx >> 3, c8 = (idx & 7) * 8;
      *reinterpret_cast<uint4*>(&Vs[r][c8]) =
          *reinterpret_cast<const uint4*>(&Vb[(size_t)r * Nk + k0 + c8]);
    }
    __syncthreads();

    // S = Q K^T  (s[i][j]: col = j*16 + c (kv), row = g*4 + r (q))
    f32x4 s[2][4];
#pragma unroll
    for (int i = 0; i < 2; i++)
#pragma unroll
      for (int j = 0; j < 4; j++) { f32x4 zz = {0.f, 0.f, 0.f, 0.f}; s[i][j] = zz; }
#pragma unroll
    for (int kk = 0; kk < 4; kk++)
#pragma unroll
      for (int j = 0; j < 4; j++) {
        bf16x8 kf = *reinterpret_cast<const bf16x8*>(&Ks[j * 16 + c][kk * 32 + g * 8]);
        s[0][j] = __builtin_amdgcn_mfma_f32_16x16x32_bf16(qf[0][kk], kf, s[0][j], 0, 0, 0);
        s[1][j] = __builtin_amdgcn_mfma_f32_16x16x32_bf16(qf[1][kk], kf, s[1][j], 0, 0, 0);
      }

    // online softmax (rows g*4+r per lane)
#pragma unroll
    for (int i = 0; i < 2; i++) {
      float mn[4], f[4], rs[4];
#pragma unroll
      for (int r = 0; r < 4; r++) {
        float tm = fmaxf(fmaxf(s[i][0][r], s[i][1][r]), fmaxf(s[i][2][r], s[i][3][r]));
        tm = fmaxf(tm, __shfl_xor(tm, 1));
        tm = fmaxf(tm, __shfl_xor(tm, 2));
        tm = fmaxf(tm, __shfl_xor(tm, 4));
        tm = fmaxf(tm, __shfl_xor(tm, 8));
        mn[r] = fmaxf(m[i][r], tm * scale);
        f[r] = __expf(m[i][r] - mn[r]);
        m[i][r] = mn[r];
        rs[r] = 0.f;
      }
#pragma unroll
      for (int j = 0; j < 4; j++)
#pragma unroll
        for (int r = 0; r < 4; r++) {
          float p = __expf(s[i][j][r] * scale - mn[r]);
          rs[r] += p;
          Ps[w * 32 + i * 16 + g * 4 + r][j * 16 + c] = __float2bfloat16(p);
        }
#pragma unroll
      for (int r = 0; r < 4; r++) {
        float t2 = rs[r];
        t2 += __shfl_xor(t2, 1);
        t2 += __shfl_xor(t2, 2);
        t2 += __shfl_xor(t2, 4);
        t2 += __shfl_xor(t2, 8);
        l[i][r] = l[i][r] * f[r] + t2;
#pragma unroll
        for (int d = 0; d < 8; d++) oa[i][d][r] *= f[r];
      }
    }

    // O += P V  (A = P[q][kv] from LDS, B = Vt[d][kv])
#pragma unroll
    for (int kk = 0; kk < 2; kk++) {
      bf16x8 pf0 = *reinterpret_cast<const bf16x8*>(&Ps[w * 32 + c][kk * 32 + g * 8]);
      bf16x8 pf1 = *reinterpret_cast<const bf16x8*>(&Ps[w * 32 + 16 + c][kk * 32 + g * 8]);
#pragma unroll
      for (int d = 0; d < 8; d++) {
        bf16x8 vf = *reinterpret_cast<const bf16x8*>(&Vs[d * 16 + c][kk * 32 + g * 8]);
        oa[0][d] = __builtin_amdgcn_mfma_f32_16x16x32_bf16(pf0, vf, oa[0][d], 0, 0, 0);
        oa[1][d] = __builtin_amdgcn_mfma_f32_16x16x32_bf16(pf1, vf, oa[1][d], 0, 0, 0);
      }
    }
    __syncthreads();
  }

#pragma unroll
  for (int i = 0; i < 2; i++) {
    float inv[4];
#pragma unroll
    for (int r = 0; r < 4; r++) inv[r] = 1.0f / l[i][r];
#pragma unroll
    for (int d = 0; d < 8; d++) {
      int col = d * 16 + c;
#pragma unroll
      for (int r = 0; r < 4; r++) {
        int row = q0 + w * 32 + i * 16 + g * 4 + r;
        Ob[(size_t)row * C + col] = __float2bfloat16(oa[i][d][r] * inv[r]);
      }
    }
  }
}

// ---------------- fused residual + LayerNorm (full tensor; A separate buffer) ----------------
__global__ __launch_bounds__(256) void k_ln(const float* __restrict__ X1, const float* __restrict__ X2,
                                            const float* __restrict__ A,
                                            const float* __restrict__ w, const float* __restrict__ bvec,
                                            float* __restrict__ outf, bf16_t* __restrict__ outb) {
  int row = blockIdx.x, tid = threadIdx.x;
  size_t base = (size_t)row * 768;
  float v0 = X1[base + tid] + A[base + tid];
  float v1 = X1[base + tid + 256] + A[base + tid + 256];
  float v2 = X1[base + tid + 512] + A[base + tid + 512];
  if (X2) {
    v0 += X2[base + tid]; v1 += X2[base + tid + 256]; v2 += X2[base + tid + 512];
  }
  float s = v0 + v1 + v2;
  for (int o = 32; o; o >>= 1) s += __shfl_xor(s, o);
  __shared__ float sm[8];
  int wv = tid >> 6, ln = tid & 63;
  if (ln == 0) sm[wv] = s;
  __syncthreads();
  s = sm[0] + sm[1] + sm[2] + sm[3];
  float mean = s * (1.0f / 768.0f);
  float d0 = v0 - mean, d1 = v1 - mean, d2 = v2 - mean;
  float ss = d0 * d0 + d1 * d1 + d2 * d2;
  for (int o = 32; o; o >>= 1) ss += __shfl_xor(ss, o);
  if (ln == 0) sm[4 + wv] = ss;
  __syncthreads();
  ss = sm[4] + sm[5] + sm[6] + sm[7];
  float rstd = rsqrtf(ss * (1.0f / 768.0f) + 1e-5f);
  float o0 = d0 * rstd * w[tid] + bvec[tid];
  float o1 = d1 * rstd * w[tid + 256] + bvec[tid + 256];
  float o2 = d2 * rstd * w[tid + 512] + bvec[tid + 512];
  outf[base + tid] = o0; outf[base + tid + 256] = o1; outf[base + tid + 512] = o2;
  if (outb) {
    outb[base + tid] = __float2bfloat16(o0);
    outb[base + tid + 256] = __float2bfloat16(o1);
    outb[base + tid + 512] = __float2bfloat16(o2);
  }
}

// ---------------- stage-3 final: out += (img + pe + flag), full tensor ----------------
__global__ __launch_bounds__(256) void k_out3f(const float* __restrict__ imA, const float* __restrict__ imB,
                                               const float* __restrict__ pe, const float* __restrict__ fa,
                                               const float* __restrict__ fb, float* __restrict__ out) {
  int idx = blockIdx.x * 256 + threadIdx.x;     // over 2B*N*(C/4)
  int c4 = idx % 192; int rem = idx / 192;
  int n = rem & 1023; int bb = rem >> 10;
  int b = bb & 3, isB = bb >> 2;
  int c = c4 * 4;
  size_t tok = (size_t)(b * 1024 + n) * 768 + c;
  float4 sv = *(const float4*)((isB ? imB : imA) + tok);
  float4 p = *(const float4*)(pe + tok);
  float4 f = *(const float4*)((isB ? fb : fa) + c);
  size_t o = (size_t)idx * 4;
  float4 cur = *(float4*)(out + o);
  cur.x += sv.x + p.x + f.x;
  cur.y += sv.y + p.y + f.y;
  cur.z += sv.z + p.z + f.z;
  cur.w += sv.w + p.w + f.w;
  *(float4*)(out + o) = cur;
}

// ---------------- bf16 MFMA GEMM: Out = X @ Wt^T + bias, optional GELU ----------------
template<int OUTBF, int GELU>
__global__ __launch_bounds__(256, 2) void k_gemm(
    const bf16_t* __restrict__ X, const bf16_t* __restrict__ Wt,
    const float* __restrict__ bias, void* __restrict__ Out,
    int M, int Nout, int K, int ldx, int ldw, int ldo) {
  const int brow = blockIdx.y * 128;
  const int bcol = blockIdx.x * 128;

  __shared__ bf16_t As[128][40];
  __shared__ bf16_t Bs[128][40];

  const int tid = threadIdx.x;
  const int lane = tid & 63;
  const int wave = tid >> 6;
  const int wr = wave >> 1;
  const int wc = wave & 1;

  f32x4 acc[4][4];
#pragma unroll
  for (int i = 0; i < 4; i++)
#pragma unroll
    for (int j = 0; j < 4; j++) {
      f32x4 zz = {0.f, 0.f, 0.f, 0.f};
      acc[i][j] = zz;
    }

  const int sr0 = tid >> 2;
  const int sc0 = (tid & 3) * 8;

  const int nK = K >> 5;
  for (int kk = 0; kk < nK; ++kk) {
    const int k0 = kk << 5;
    uint4 v0 = *reinterpret_cast<const uint4*>(X + (size_t)(brow + sr0) * ldx + k0 + sc0);
    uint4 v1 = *reinterpret_cast<const uint4*>(X + (size_t)(brow + 64 + sr0) * ldx + k0 + sc0);
    uint4 w0 = *reinterpret_cast<const uint4*>(Wt + (size_t)(bcol + sr0) * ldw + k0 + sc0);
    uint4 w1 = *reinterpret_cast<const uint4*>(Wt + (size_t)(bcol + 64 + sr0) * ldw + k0 + sc0);
    __syncthreads();
    *reinterpret_cast<uint4*>(&As[sr0][sc0]) = v0;
    *reinterpret_cast<uint4*>(&As[64 + sr0][sc0]) = v1;
    *reinterpret_cast<uint4*>(&Bs[sr0][sc0]) = w0;
    *reinterpret_cast<uint4*>(&Bs[64 + sr0][sc0]) = w1;
    __syncthreads();

    bf16x8 afr[4], bfr[4];
    const int lrow = lane & 15;
    const int kch = (lane >> 4) * 8;
#pragma unroll
    for (int i = 0; i < 4; i++)
      afr[i] = *reinterpret_cast<const bf16x8*>(&As[wr * 64 + i * 16 + lrow][kch]);
#pragma unroll
    for (int j = 0; j < 4; j++)
      bfr[j] = *reinterpret_cast<const bf16x8*>(&Bs[wc * 64 + j * 16 + lrow][kch]);
#pragma unroll
    for (int i = 0; i < 4; i++)
#pragma unroll
      for (int j = 0; j < 4; j++)
        acc[i][j] = __builtin_amdgcn_mfma_f32_16x16x32_bf16(afr[i], bfr[j], acc[i][j], 0, 0, 0);
  }

  const int lcol = lane & 15;
  const int lrow4 = (lane >> 4) * 4;
#pragma unroll
  for (int i = 0; i < 4; i++) {
    int row0 = brow + wr * 64 + i * 16 + lrow4;
#pragma unroll
    for (int j = 0; j < 4; j++) {
      int col = bcol + wc * 64 + j * 16 + lcol;
      float bv = bias ? bias[col] : 0.0f;
#pragma unroll
      for (int r = 0; r < 4; r++) {
        float v = acc[i][j][r] + bv;
        if (GELU) v = 0.5f * v * (1.0f + erff(v * 0.70710678118f));
        size_t idx = (size_t)(row0 + r) * ldo + col;
        if (OUTBF) reinterpret_cast<bf16_t*>(Out)[idx] = __float2bfloat16(v);
        else reinterpret_cast<float*>(Out)[idx] = v;
      }
    }
  }
}

static inline void gemm(hipStream_t st, const bf16_t* X, const bf16_t* Wt, const float* bias,
                        void* out, int outBf, int gelu, int M, int N, int K,
                        int ldx, int ldw, int ldo) {
  dim3 g(N / 128, M / 128), blk(256);
  if (outBf) {
    if (gelu) k_gemm<1, 1><<<g, blk, 0, st>>>(X, Wt, bias, out, M, N, K, ldx, ldw, ldo);
    else      k_gemm<1, 0><<<g, blk, 0, st>>>(X, Wt, bias, out, M, N, K, ldx, ldw, ldo);
  } else      k_gemm<0, 0><<<g, blk, 0, st>>>(X, Wt, bias, out, M, N, K, ldx, ldw, ldo);
}

extern "C" void kernel_launch(void* const* d_in, const int* in_sizes, int n_in,
                              void* d_out, int out_size, void* d_ws, size_t ws_size,
                              hipStream_t stream) {
  (void)in_sizes; (void)n_in; (void)out_size; (void)ws_size;
  constexpr int B = 4, N = 1024, C = 768, Hh = 6, MLPD = 2304;
  constexpr size_t BNC = (size_t)B * N * C;
  constexpr size_t NC  = (size_t)N * C;
  const float scale = 0.08838834764831845f;   // 1/sqrt(128)

  const float* queries = (const float*)d_in[0];
  const float* change  = (const float*)d_in[1];
  const float* imA     = (const float*)d_in[2];
  const float* imB     = (const float*)d_in[3];
  const float* pe      = (const float*)d_in[4];
  const float* bq1 = (const float*)d_in[6];  const float* bk1 = (const float*)d_in[8];
  const float* bv1 = (const float*)d_in[10]; const float* bo1 = (const float*)d_in[12];
  const float* bq2 = (const float*)d_in[14]; const float* bk2 = (const float*)d_in[16];
  const float* bv2 = (const float*)d_in[18]; const float* bo2 = (const float*)d_in[20];
  const float* bq3 = (const float*)d_in[22]; const float* bk3 = (const float*)d_in[24];
  const float* bv3 = (const float*)d_in[26]; const float* bo3 = (const float*)d_in[28];
  const float* ln1w = (const float*)d_in[29]; const float* ln1b = (const float*)d_in[30];
  const float* ln2w = (const float*)d_in[31]; const float* ln2b = (const float*)d_in[32];
  const float* ln3w = (const float*)d_in[33]; const float* ln3b = (const float*)d_in[34];
  const float* mb1 = (const float*)d_in[36]; const float* mb2 = (const float*)d_in[38];
  const float* fa = (const float*)d_in[39];
  const float* fb = (const float*)d_in[40];
  const float* fc = (const float*)d_in[41];

  char* base = (char*)d_ws;
  size_t off = 0;
  auto alloc = [&](size_t bytes) -> void* {
    void* p = base + off;
    off += (bytes + 255) & ~(size_t)255;
    return p;
  };

  // ---- persistent ----
  bf16_t* WT[14];
  const int widx[14] = {5, 7, 9, 11, 13, 15, 17, 19, 21, 23, 25, 27, 35, 37};
  const int wins[14] = {768, 768, 768, 768, 768, 768, 768, 768, 768, 768, 768, 768, 768, 2304};
  const int wout[14] = {768, 768, 768, 768, 768, 768, 768, 768, 768, 768, 768, 768, 2304, 768};
  for (int i = 0; i < 14; i++) WT[i] = (bf16_t*)alloc((size_t)wins[i] * wout[i] * 2);
  float*  q1  = (float*)alloc(BNC * 4);
  float*  q2  = (float*)alloc(BNC * 4);
  bf16_t* q2b = (bf16_t*)alloc(BNC * 2);
  const size_t arena = off;

  float* dof = (float*)d_out;                  // [0,2BNC) images, [2BNC,3BNC) change
  float* chg = dof + 2 * BNC;

  for (int i = 0; i < 14; i++) {
    dim3 g(wins[i] / 32, wout[i] / 32);
    k_wt<<<g, 256, 0, stream>>>((const float*)d_in[widx[i]], WT[i], wins[i], wout[i]);
  }

  // ================= stage 1: self-attention (full batch) =================
  off = arena;
  bf16_t* qpe_b = (bf16_t*)alloc(BNC * 2);
  bf16_t* q0_b  = (bf16_t*)alloc(BNC * 2);
  bf16_t* Qh    = (bf16_t*)alloc(BNC * 2);
  bf16_t* Kh    = (bf16_t*)alloc(BNC * 2);
  bf16_t* Vh    = (bf16_t*)alloc(BNC * 2);
  bf16_t* vT1   = (bf16_t*)alloc(BNC * 2);
  bf16_t* attC  = (bf16_t*)alloc(BNC * 2);
  float*  a1    = dof;                          // scratch in d_out

  k_prep1<<<dim3((int)(BNC / 4 / 256)), 256, 0, stream>>>(
      (const float4*)queries, (const float4*)change, (const float4*)pe, qpe_b, q0_b, (int)(BNC / 4));
  gemm(stream, qpe_b, WT[0], bq1, Qh, 1, 0, B * N, C, C, C, C, C);
  gemm(stream, qpe_b, WT[1], bk1, Kh, 1, 0, B * N, C, C, C, C, C);
  gemm(stream, q0_b,  WT[2], bv1, Vh, 1, 0, B * N, C, C, C, C, C);
  k_vt<<<dim3(N / 32, 4, B * Hh), 256, 0, stream>>>(Vh, vT1, N, C, Hh);
  k_flash<<<dim3(N / 128, B * Hh), 256, 0, stream>>>(Qh, Kh, vT1, attC, N, C, Hh, scale,
                                                     (long)NC, (long)NC);
  gemm(stream, attC, WT[3], bo1, a1, 0, 0, B * N, C, C, C, C, C);
  k_ln<<<dim3(B * N), 256, 0, stream>>>(queries, change, a1, ln1w, ln1b, q1, (bf16_t*)nullptr);

  // ================= stage 2: cross-attn change -> [A,B,change] =================
  off = arena;
  bf16_t* qf    = (bf16_t*)alloc(BNC * 2);
  bf16_t* Q2h   = (bf16_t*)alloc(BNC * 2);
  bf16_t* attC2 = (bf16_t*)alloc(BNC * 2);
  bf16_t* k2in  = (bf16_t*)alloc(3 * NC * 2);
  bf16_t* v2in  = (bf16_t*)alloc(3 * NC * 2);
  bf16_t* K2h   = (bf16_t*)alloc(3 * NC * 2);
  bf16_t* V2h   = (bf16_t*)alloc(3 * NC * 2);
  bf16_t* vT2   = (bf16_t*)alloc(3 * NC * 2);
  float*  a2    = dof;

  k_addpe<<<dim3((int)(BNC / 4 / 256)), 256, 0, stream>>>(q1, pe, fc, qf);
  gemm(stream, qf, WT[4], bq2, Q2h, 1, 0, B * N, C, C, C, C, C);
  for (int b = 0; b < B; ++b) {
    const int Nk = 3 * N;
    k_build2b<<<dim3((int)(3 * NC / 4 / 256)), 256, 0, stream>>>(
        q1, imA, imB, pe, fa, fb, fc, k2in, v2in, b);
    gemm(stream, k2in, WT[5], bk2, K2h, 1, 0, Nk, C, C, C, C, C);
    gemm(stream, v2in, WT[6], bv2, V2h, 1, 0, Nk, C, C, C, C, C);
    k_vt<<<dim3(Nk / 32, 4, Hh), 256, 0, stream>>>(V2h, vT2, Nk, C, Hh);
    k_flash<<<dim3(N / 128, Hh), 256, 0, stream>>>(Q2h + (size_t)b * NC, K2h, vT2,
                                                   attC2 + (size_t)b * NC, Nk, C, Hh, scale, 0, 0);
  }
  gemm(stream, attC2, WT[7], bo2, a2, 0, 0, B * N, C, C, C, C, C);
  k_ln<<<dim3(B * N), 256, 0, stream>>>(q1, (const float*)nullptr, a2, ln2w, ln2b, q2, q2b);

  // ================= MLP =================
  off = arena;
  bf16_t* h1 = (bf16_t*)alloc((size_t)B * N * MLPD * 2);
  float*  a3 = dof;
  gemm(stream, q2b, WT[12], mb1, h1, 1, 1, B * N, MLPD, C, C, C, MLPD);
  gemm(stream, h1, WT[13], mb2, a3, 0, 0, B * N, C, MLPD, MLPD, MLPD, C);
  k_ln<<<dim3(B * N), 256, 0, stream>>>(q2, (const float*)nullptr, a3, ln3w, ln3b, chg, (bf16_t*)nullptr);

  // ================= stage 3: [A;B] -> [image;change] =================
  off = arena;
  bf16_t* qq    = (bf16_t*)alloc(2 * BNC * 2);
  bf16_t* Q3h   = (bf16_t*)alloc(2 * BNC * 2);
  bf16_t* attC3 = (bf16_t*)alloc(2 * BNC * 2);
  bf16_t* k3in  = (bf16_t*)alloc(2 * NC * 2);
  bf16_t* v3in  = (bf16_t*)alloc(2 * NC * 2);
  bf16_t* K3h   = (bf16_t*)alloc(2 * NC * 2);
  bf16_t* V3h   = (bf16_t*)alloc(2 * NC * 2);
  bf16_t* vT3   = (bf16_t*)alloc(2 * NC * 2);

  k_buildqq<<<dim3((int)(2 * BNC / 4 / 256)), 256, 0, stream>>>(imA, imB, pe, fa, fb, qq);
  gemm(stream, qq, WT[8], bq3, Q3h, 1, 0, 2 * B * N, C, C, C, C, C);
  for (int bb = 0; bb < 2 * B; ++bb) {
    const int Nk = 2 * N;
    k_build3b<<<dim3((int)(2 * NC / 4 / 256)), 256, 0, stream>>>(
        chg, imA, imB, pe, fa, fb, fc, k3in, v3in, bb);
    gemm(stream, k3in, WT[9],  bk3, K3h, 1, 0, Nk, C, C, C, C, C);
    gemm(stream, v3in, WT[10], bv3, V3h, 1, 0, Nk, C, C, C, C, C);
    k_vt<<<dim3(Nk / 32, 4, Hh), 256, 0, stream>>>(V3h, vT3, Nk, C, Hh);
    k_flash<<<dim3(N / 128, Hh), 256, 0, stream>>>(Q3h + (size_t)bb * NC, K3h, vT3,
                                                   attC3 + (size_t)bb * NC, Nk, C, Hh, scale, 0, 0);
  }
  gemm(stream, attC3, WT[11], bo3, dof, 0, 0, 2 * B * N, C, C, C, C, C);
  k_out3f<<<dim3((int)(2 * BNC / 4 / 256)), 256, 0, stream>>>(imA, imB, pe, fa, fb, dof);
}

// Round 4
// 966.863 us; speedup vs baseline: 3.7585x; 2.3571x over previous
//
#include <hip/hip_runtime.h>
#include <hip/hip_bf16.h>
#include <math.h>

typedef short bf16x8 __attribute__((ext_vector_type(8)));
typedef float f32x4 __attribute__((ext_vector_type(4)));
using bf16_t = __hip_bfloat16;

#define DEV static __device__ __forceinline__

DEV unsigned short f2bu(float x) {
  bf16_t h = __float2bfloat16(x);
  unsigned short u;
  __builtin_memcpy(&u, &h, 2);
  return u;
}
DEV void st4(bf16_t* p, float a, float b, float c, float d) {
  ushort4 u;
  u.x = f2bu(a); u.y = f2bu(b); u.z = f2bu(c); u.w = f2bu(d);
  *reinterpret_cast<ushort4*>(p) = u;
}

// ---------------- weight transpose + bf16 convert: W[in][out] -> WT[out][in] ----------------
__global__ __launch_bounds__(256) void k_wt(const float* __restrict__ W, bf16_t* __restrict__ WT,
                                            int in_dim, int out_dim) {
  __shared__ float tile[32][33];
  int i0 = blockIdx.x * 32;
  int o0 = blockIdx.y * 32;
  int tx = threadIdx.x & 31, ty = threadIdx.x >> 5;
  for (int r = ty; r < 32; r += 8)
    tile[r][tx] = W[(size_t)(i0 + r) * out_dim + (o0 + tx)];
  __syncthreads();
  for (int r = ty; r < 32; r += 8)
    WT[(size_t)(o0 + r) * in_dim + (i0 + tx)] = __float2bfloat16(tile[tx][r]);
}

// ---------------- stage-1 elementwise prep ----------------
__global__ __launch_bounds__(256) void k_prep1(const float4* __restrict__ q, const float4* __restrict__ ce,
                                               const float4* __restrict__ pe,
                                               bf16_t* __restrict__ qpe_b, bf16_t* __restrict__ q0_b, int n4) {
  int i = blockIdx.x * 256 + threadIdx.x;
  if (i >= n4) return;
  float4 a = q[i], b = ce[i], p = pe[i];
  float sx = a.x + b.x, sy = a.y + b.y, sz = a.z + b.z, sw = a.w + b.w;
  st4(q0_b + 4 * (size_t)i, sx, sy, sz, sw);
  st4(qpe_b + 4 * (size_t)i, sx + p.x, sy + p.y, sz + p.z, sw + p.w);
}

// ---------------- out[row] = x[row] + pe[row] + flag (bf16), rows = B*N ----------------
__global__ __launch_bounds__(256) void k_addpe(const float* __restrict__ x, const float* __restrict__ pe,
                                               const float* __restrict__ flag, bf16_t* __restrict__ out) {
  int idx = blockIdx.x * 256 + threadIdx.x;
  int c = (idx % 192) * 4;
  size_t tok = (size_t)idx * 4;
  float4 xv = *(const float4*)(x + tok);
  float4 p = *(const float4*)(pe + tok);
  float4 f = *(const float4*)(flag + c);
  st4(out + tok, xv.x + p.x + f.x, xv.y + p.y + f.y, xv.z + p.z + f.z, xv.w + p.w + f.w);
}

// ---------------- build qq for cross-attn 3 (rows = 2B*N) ----------------
__global__ __launch_bounds__(256) void k_buildqq(const float* __restrict__ imA, const float* __restrict__ imB,
                                                 const float* __restrict__ pe, const float* __restrict__ fa,
                                                 const float* __restrict__ fb, bf16_t* __restrict__ qq) {
  int idx = blockIdx.x * 256 + threadIdx.x;
  int c4 = idx % 192; int rem = idx / 192;
  int n = rem & 1023; int bb = rem >> 10;
  int b = bb & 3, isB = bb >> 2;
  int c = c4 * 4;
  size_t tok = (size_t)(b * 1024 + n) * 768 + c;
  float4 s = *(const float4*)((isB ? imB : imA) + tok);
  float4 p = *(const float4*)(pe + tok);
  float4 f = *(const float4*)((isB ? fb : fa) + c);
  st4(qq + (size_t)rem * 768 + c, s.x + p.x + f.x, s.y + p.y + f.y, s.z + p.z + f.z, s.w + p.w + f.w);
}

// ---------------- build K2/V2 for cross-attn 2, single batch b ----------------
__global__ __launch_bounds__(256) void k_build2b(const float* __restrict__ q1,
    const float* __restrict__ imA, const float* __restrict__ imB, const float* __restrict__ pe,
    const float* __restrict__ fa, const float* __restrict__ fb, const float* __restrict__ fc,
    bf16_t* __restrict__ k2, bf16_t* __restrict__ v2, int b) {
  int idx = blockIdx.x * 256 + threadIdx.x;     // over 3N*(C/4)
  int c4 = idx % 192; int rem = idx / 192;
  int seg = rem >> 10; int n = rem & 1023;
  int c = c4 * 4;
  size_t tok = (size_t)(b * 1024 + n) * 768 + c;
  float4 p = *(const float4*)(pe + tok);
  const float* srcp; const float* flg;
  if (seg == 0)      { srcp = imA + tok; flg = fa; }
  else if (seg == 1) { srcp = imB + tok; flg = fb; }
  else               { srcp = q1 + tok; flg = fc; }
  float4 s = *(const float4*)srcp;
  float4 f = *(const float4*)(flg + c);
  size_t o = (size_t)idx * 4;
  st4(v2 + o, s.x, s.y, s.z, s.w);
  st4(k2 + o, s.x + p.x + f.x, s.y + p.y + f.y, s.z + p.z + f.z, s.w + p.w + f.w);
}

// ---------------- build K3/V3 for cross-attn 3, single "bb" ----------------
__global__ __launch_bounds__(256) void k_build3b(const float* __restrict__ q3,
    const float* __restrict__ imA, const float* __restrict__ imB, const float* __restrict__ pe,
    const float* __restrict__ fa, const float* __restrict__ fb, const float* __restrict__ fc,
    bf16_t* __restrict__ k3, bf16_t* __restrict__ v3, int bb) {
  int idx = blockIdx.x * 256 + threadIdx.x;     // over 2N*(C/4)
  int c4 = idx % 192; int rem = idx / 192;
  int seg = rem >> 10; int n = rem & 1023;
  int b = bb & 3; int isB = bb >> 2;
  int c = c4 * 4;
  size_t tok = (size_t)(b * 1024 + n) * 768 + c;
  float4 p = *(const float4*)(pe + tok);
  const float* srcp; const float* flg;
  if (seg == 0) { srcp = (isB ? imB : imA) + tok; flg = isB ? fb : fa; }
  else          { srcp = q3 + tok; flg = fc; }
  float4 s = *(const float4*)srcp;
  float4 f = *(const float4*)(flg + c);
  size_t o = (size_t)idx * 4;
  st4(v3 + o, s.x, s.y, s.z, s.w);
  st4(k3 + o, s.x + p.x + f.x, s.y + p.y + f.y, s.z + p.z + f.z, s.w + p.w + f.w);
}

// ---------------- V transpose: [b,Nk,H*D] -> [z=(b,h)][D][Nk] ----------------
__global__ __launch_bounds__(256) void k_vt(const bf16_t* __restrict__ V, bf16_t* __restrict__ vT,
                                            int Nk, int C, int H) {
  int z = blockIdx.z; int b = z / H, h = z % H;
  int n0 = blockIdx.x * 32, d0 = blockIdx.y * 32;
  __shared__ bf16_t t[32][33];
  const bf16_t* src = V + (size_t)b * Nk * C + h * 128;
  bf16_t* dst = vT + (size_t)z * 128 * Nk;
  int tx = threadIdx.x & 31, ty = threadIdx.x >> 5;
  for (int r = ty; r < 32; r += 8) t[r][tx] = src[(size_t)(n0 + r) * C + d0 + tx];
  __syncthreads();
  for (int r = ty; r < 32; r += 8)
    dst[(size_t)(d0 + r) * Nk + n0 + tx] = t[tx][r];
}

// ---------------- flash attention: O = softmax(Q K^T) V  (scale pre-folded into Q) ----------------
__global__ __launch_bounds__(256, 2) void k_flash(
    const bf16_t* __restrict__ Q, const bf16_t* __restrict__ K,
    const bf16_t* __restrict__ Vt, bf16_t* __restrict__ O,
    int Nk, int C, int H, long qStrideB, long kStrideB) {
  const int z = blockIdx.y; const int b = z / H, h = z % H;
  const bf16_t* Qb = Q + (size_t)b * qStrideB + h * 128;
  const bf16_t* Kb = K + (size_t)b * kStrideB + h * 128;
  const bf16_t* Vb = Vt + (size_t)z * 128 * Nk;
  bf16_t* Ob = O + (size_t)b * qStrideB + h * 128;
  const int q0 = blockIdx.x * 128;
  const int tid = threadIdx.x, lane = tid & 63, w = tid >> 6;
  const int g = lane >> 4, c = lane & 15;

  __shared__ bf16_t Ks[64][136];
  __shared__ bf16_t Vs[128][72];
  __shared__ bf16_t Ps[128][72];

  bf16x8 qf[2][4];
#pragma unroll
  for (int i = 0; i < 2; i++)
#pragma unroll
    for (int kk = 0; kk < 4; kk++)
      qf[i][kk] = *reinterpret_cast<const bf16x8*>(
          &Qb[(size_t)(q0 + w * 32 + i * 16 + c) * C + kk * 32 + g * 8]);

  f32x4 oa[2][8];
  float m[2][4], l[2][4];
#pragma unroll
  for (int i = 0; i < 2; i++) {
#pragma unroll
    for (int d = 0; d < 8; d++) { f32x4 zz = {0.f, 0.f, 0.f, 0.f}; oa[i][d] = zz; }
#pragma unroll
    for (int r = 0; r < 4; r++) { m[i][r] = -1.0e30f; l[i][r] = 0.f; }
  }

  const int nt = Nk >> 6;
  for (int t = 0; t < nt; ++t) {
    const int k0 = t << 6;
#pragma unroll
    for (int p = 0; p < 4; p++) {
      int idx = p * 256 + tid;
      int r = idx >> 4, c8 = (idx & 15) * 8;
      *reinterpret_cast<uint4*>(&Ks[r][c8]) =
          *reinterpret_cast<const uint4*>(&Kb[(size_t)(k0 + r) * C + c8]);
    }
#pragma unroll
    for (int p = 0; p < 4; p++) {
      int idx = p * 256 + tid;
      int r = idx >> 3, c8 = (idx & 7) * 8;
      *reinterpret_cast<uint4*>(&Vs[r][c8]) =
          *reinterpret_cast<const uint4*>(&Vb[(size_t)r * Nk + k0 + c8]);
    }
    __syncthreads();

    f32x4 s[2][4];
#pragma unroll
    for (int i = 0; i < 2; i++)
#pragma unroll
      for (int j = 0; j < 4; j++) { f32x4 zz = {0.f, 0.f, 0.f, 0.f}; s[i][j] = zz; }
#pragma unroll
    for (int kk = 0; kk < 4; kk++)
#pragma unroll
      for (int j = 0; j < 4; j++) {
        bf16x8 kf = *reinterpret_cast<const bf16x8*>(&Ks[j * 16 + c][kk * 32 + g * 8]);
        s[0][j] = __builtin_amdgcn_mfma_f32_16x16x32_bf16(qf[0][kk], kf, s[0][j], 0, 0, 0);
        s[1][j] = __builtin_amdgcn_mfma_f32_16x16x32_bf16(qf[1][kk], kf, s[1][j], 0, 0, 0);
      }

    // online softmax (rows g*4+r per lane)
#pragma unroll
    for (int i = 0; i < 2; i++) {
      float mn[4], f[4], rs[4];
#pragma unroll
      for (int r = 0; r < 4; r++) {
        float tm = fmaxf(fmaxf(s[i][0][r], s[i][1][r]), fmaxf(s[i][2][r], s[i][3][r]));
        tm = fmaxf(tm, __shfl_xor(tm, 1));
        tm = fmaxf(tm, __shfl_xor(tm, 2));
        tm = fmaxf(tm, __shfl_xor(tm, 4));
        tm = fmaxf(tm, __shfl_xor(tm, 8));
        mn[r] = fmaxf(m[i][r], tm);
        f[r] = __expf(m[i][r] - mn[r]);
        m[i][r] = mn[r];
        rs[r] = 0.f;
      }
#pragma unroll
      for (int j = 0; j < 4; j++)
#pragma unroll
        for (int r = 0; r < 4; r++) {
          float p = __expf(s[i][j][r] - mn[r]);
          rs[r] += p;
          Ps[w * 32 + i * 16 + g * 4 + r][j * 16 + c] = __float2bfloat16(p);
        }
#pragma unroll
      for (int r = 0; r < 4; r++) {
        float t2 = rs[r];
        t2 += __shfl_xor(t2, 1);
        t2 += __shfl_xor(t2, 2);
        t2 += __shfl_xor(t2, 4);
        t2 += __shfl_xor(t2, 8);
        l[i][r] = l[i][r] * f[r] + t2;
#pragma unroll
        for (int d = 0; d < 8; d++) oa[i][d][r] *= f[r];
      }
    }

    // O += P V
#pragma unroll
    for (int kk = 0; kk < 2; kk++) {
      bf16x8 pf0 = *reinterpret_cast<const bf16x8*>(&Ps[w * 32 + c][kk * 32 + g * 8]);
      bf16x8 pf1 = *reinterpret_cast<const bf16x8*>(&Ps[w * 32 + 16 + c][kk * 32 + g * 8]);
#pragma unroll
      for (int d = 0; d < 8; d++) {
        bf16x8 vf = *reinterpret_cast<const bf16x8*>(&Vs[d * 16 + c][kk * 32 + g * 8]);
        oa[0][d] = __builtin_amdgcn_mfma_f32_16x16x32_bf16(pf0, vf, oa[0][d], 0, 0, 0);
        oa[1][d] = __builtin_amdgcn_mfma_f32_16x16x32_bf16(pf1, vf, oa[1][d], 0, 0, 0);
      }
    }
    __syncthreads();
  }

#pragma unroll
  for (int i = 0; i < 2; i++) {
    float inv[4];
#pragma unroll
    for (int r = 0; r < 4; r++) inv[r] = 1.0f / l[i][r];
#pragma unroll
    for (int d = 0; d < 8; d++) {
      int col = d * 16 + c;
#pragma unroll
      for (int r = 0; r < 4; r++) {
        int row = q0 + w * 32 + i * 16 + g * 4 + r;
        Ob[(size_t)row * C + col] = __float2bfloat16(oa[i][d][r] * inv[r]);
      }
    }
  }
}

// ---------------- fused residual + LayerNorm ----------------
__global__ __launch_bounds__(256) void k_ln(const float* __restrict__ X1, const float* __restrict__ X2,
                                            const float* __restrict__ A,
                                            const float* __restrict__ w, const float* __restrict__ bvec,
                                            float* __restrict__ outf, bf16_t* __restrict__ outb) {
  int row = blockIdx.x, tid = threadIdx.x;
  size_t base = (size_t)row * 768;
  float v0 = X1[base + tid] + A[base + tid];
  float v1 = X1[base + tid + 256] + A[base + tid + 256];
  float v2 = X1[base + tid + 512] + A[base + tid + 512];
  if (X2) {
    v0 += X2[base + tid]; v1 += X2[base + tid + 256]; v2 += X2[base + tid + 512];
  }
  float s = v0 + v1 + v2;
  for (int o = 32; o; o >>= 1) s += __shfl_xor(s, o);
  __shared__ float sm[8];
  int wv = tid >> 6, ln = tid & 63;
  if (ln == 0) sm[wv] = s;
  __syncthreads();
  s = sm[0] + sm[1] + sm[2] + sm[3];
  float mean = s * (1.0f / 768.0f);
  float d0 = v0 - mean, d1 = v1 - mean, d2 = v2 - mean;
  float ss = d0 * d0 + d1 * d1 + d2 * d2;
  for (int o = 32; o; o >>= 1) ss += __shfl_xor(ss, o);
  if (ln == 0) sm[4 + wv] = ss;
  __syncthreads();
  ss = sm[4] + sm[5] + sm[6] + sm[7];
  float rstd = rsqrtf(ss * (1.0f / 768.0f) + 1e-5f);
  float o0 = d0 * rstd * w[tid] + bvec[tid];
  float o1 = d1 * rstd * w[tid + 256] + bvec[tid + 256];
  float o2 = d2 * rstd * w[tid + 512] + bvec[tid + 512];
  outf[base + tid] = o0; outf[base + tid + 256] = o1; outf[base + tid + 512] = o2;
  if (outb) {
    outb[base + tid] = __float2bfloat16(o0);
    outb[base + tid + 256] = __float2bfloat16(o1);
    outb[base + tid + 512] = __float2bfloat16(o2);
  }
}

// ---------------- stage-3 final: out += (img + pe + flag) ----------------
__global__ __launch_bounds__(256) void k_out3f(const float* __restrict__ imA, const float* __restrict__ imB,
                                               const float* __restrict__ pe, const float* __restrict__ fa,
                                               const float* __restrict__ fb, float* __restrict__ out) {
  int idx = blockIdx.x * 256 + threadIdx.x;
  int c4 = idx % 192; int rem = idx / 192;
  int n = rem & 1023; int bb = rem >> 10;
  int b = bb & 3, isB = bb >> 2;
  int c = c4 * 4;
  size_t tok = (size_t)(b * 1024 + n) * 768 + c;
  float4 sv = *(const float4*)((isB ? imB : imA) + tok);
  float4 p = *(const float4*)(pe + tok);
  float4 f = *(const float4*)((isB ? fb : fa) + c);
  size_t o = (size_t)idx * 4;
  float4 cur = *(float4*)(out + o);
  cur.x += sv.x + p.x + f.x;
  cur.y += sv.y + p.y + f.y;
  cur.z += sv.z + p.z + f.z;
  cur.w += sv.w + p.w + f.w;
  *(float4*)(out + o) = cur;
}

// ---------------- bf16 MFMA GEMM: Out = alpha*(X @ Wt^T + bias), optional GELU ----------------
template<int OUTBF, int GELU>
__global__ __launch_bounds__(256, 2) void k_gemm(
    const bf16_t* __restrict__ X, const bf16_t* __restrict__ Wt,
    const float* __restrict__ bias, void* __restrict__ Out,
    int M, int Nout, int K, int ldx, int ldw, int ldo, float alpha) {
  const int brow = blockIdx.y * 128;
  const int bcol = blockIdx.x * 128;

  __shared__ bf16_t As[128][40];
  __shared__ bf16_t Bs[128][40];

  const int tid = threadIdx.x;
  const int lane = tid & 63;
  const int wave = tid >> 6;
  const int wr = wave >> 1;
  const int wc = wave & 1;

  f32x4 acc[4][4];
#pragma unroll
  for (int i = 0; i < 4; i++)
#pragma unroll
    for (int j = 0; j < 4; j++) {
      f32x4 zz = {0.f, 0.f, 0.f, 0.f};
      acc[i][j] = zz;
    }

  const int sr0 = tid >> 2;
  const int sc0 = (tid & 3) * 8;

  const int nK = K >> 5;
  for (int kk = 0; kk < nK; ++kk) {
    const int k0 = kk << 5;
    uint4 v0 = *reinterpret_cast<const uint4*>(X + (size_t)(brow + sr0) * ldx + k0 + sc0);
    uint4 v1 = *reinterpret_cast<const uint4*>(X + (size_t)(brow + 64 + sr0) * ldx + k0 + sc0);
    uint4 w0 = *reinterpret_cast<const uint4*>(Wt + (size_t)(bcol + sr0) * ldw + k0 + sc0);
    uint4 w1 = *reinterpret_cast<const uint4*>(Wt + (size_t)(bcol + 64 + sr0) * ldw + k0 + sc0);
    __syncthreads();
    *reinterpret_cast<uint4*>(&As[sr0][sc0]) = v0;
    *reinterpret_cast<uint4*>(&As[64 + sr0][sc0]) = v1;
    *reinterpret_cast<uint4*>(&Bs[sr0][sc0]) = w0;
    *reinterpret_cast<uint4*>(&Bs[64 + sr0][sc0]) = w1;
    __syncthreads();

    bf16x8 afr[4], bfr[4];
    const int lrow = lane & 15;
    const int kch = (lane >> 4) * 8;
#pragma unroll
    for (int i = 0; i < 4; i++)
      afr[i] = *reinterpret_cast<const bf16x8*>(&As[wr * 64 + i * 16 + lrow][kch]);
#pragma unroll
    for (int j = 0; j < 4; j++)
      bfr[j] = *reinterpret_cast<const bf16x8*>(&Bs[wc * 64 + j * 16 + lrow][kch]);
#pragma unroll
    for (int i = 0; i < 4; i++)
#pragma unroll
      for (int j = 0; j < 4; j++)
        acc[i][j] = __builtin_amdgcn_mfma_f32_16x16x32_bf16(afr[i], bfr[j], acc[i][j], 0, 0, 0);
  }

  const int lcol = lane & 15;
  const int lrow4 = (lane >> 4) * 4;
#pragma unroll
  for (int i = 0; i < 4; i++) {
    int row0 = brow + wr * 64 + i * 16 + lrow4;
#pragma unroll
    for (int j = 0; j < 4; j++) {
      int col = bcol + wc * 64 + j * 16 + lcol;
      float bv = bias ? bias[col] : 0.0f;
#pragma unroll
      for (int r = 0; r < 4; r++) {
        float v = (acc[i][j][r] + bv) * alpha;
        if (GELU) v = 0.5f * v * (1.0f + erff(v * 0.70710678118f));
        size_t idx = (size_t)(row0 + r) * ldo + col;
        if (OUTBF) reinterpret_cast<bf16_t*>(Out)[idx] = __float2bfloat16(v);
        else reinterpret_cast<float*>(Out)[idx] = v;
      }
    }
  }
}

static inline void gemm(hipStream_t st, const bf16_t* X, const bf16_t* Wt, const float* bias,
                        void* out, int outBf, int gelu, int M, int N, int K,
                        int ldx, int ldw, int ldo, float alpha = 1.0f) {
  dim3 g(N / 128, M / 128), blk(256);
  if (outBf) {
    if (gelu) k_gemm<1, 1><<<g, blk, 0, st>>>(X, Wt, bias, out, M, N, K, ldx, ldw, ldo, alpha);
    else      k_gemm<1, 0><<<g, blk, 0, st>>>(X, Wt, bias, out, M, N, K, ldx, ldw, ldo, alpha);
  } else      k_gemm<0, 0><<<g, blk, 0, st>>>(X, Wt, bias, out, M, N, K, ldx, ldw, ldo, alpha);
}

extern "C" void kernel_launch(void* const* d_in, const int* in_sizes, int n_in,
                              void* d_out, int out_size, void* d_ws, size_t ws_size,
                              hipStream_t stream) {
  (void)in_sizes; (void)n_in; (void)out_size;
  constexpr int B = 4, N = 1024, C = 768, Hh = 6, MLPD = 2304;
  constexpr size_t BNC = (size_t)B * N * C;
  constexpr size_t NC  = (size_t)N * C;
  const float scale = 0.08838834764831845f;   // 1/sqrt(128)

  const float* queries = (const float*)d_in[0];
  const float* change  = (const float*)d_in[1];
  const float* imA     = (const float*)d_in[2];
  const float* imB     = (const float*)d_in[3];
  const float* pe      = (const float*)d_in[4];
  const float* bq1 = (const float*)d_in[6];  const float* bk1 = (const float*)d_in[8];
  const float* bv1 = (const float*)d_in[10]; const float* bo1 = (const float*)d_in[12];
  const float* bq2 = (const float*)d_in[14]; const float* bk2 = (const float*)d_in[16];
  const float* bv2 = (const float*)d_in[18]; const float* bo2 = (const float*)d_in[20];
  const float* bq3 = (const float*)d_in[22]; const float* bk3 = (const float*)d_in[24];
  const float* bv3 = (const float*)d_in[26]; const float* bo3 = (const float*)d_in[28];
  const float* ln1w = (const float*)d_in[29]; const float* ln1b = (const float*)d_in[30];
  const float* ln2w = (const float*)d_in[31]; const float* ln2b = (const float*)d_in[32];
  const float* ln3w = (const float*)d_in[33]; const float* ln3b = (const float*)d_in[34];
  const float* mb1 = (const float*)d_in[36]; const float* mb2 = (const float*)d_in[38];
  const float* fa = (const float*)d_in[39];
  const float* fb = (const float*)d_in[40];
  const float* fc = (const float*)d_in[41];

  char* base = (char*)d_ws;
  size_t off = 0;
  auto alloc = [&](size_t bytes) -> void* {
    void* p = base + off;
    off += (bytes + 255) & ~(size_t)255;
    return p;
  };

  // ---- persistent ----
  bf16_t* WT[14];
  const int widx[14] = {5, 7, 9, 11, 13, 15, 17, 19, 21, 23, 25, 27, 35, 37};
  const int wins[14] = {768, 768, 768, 768, 768, 768, 768, 768, 768, 768, 768, 768, 768, 2304};
  const int wout[14] = {768, 768, 768, 768, 768, 768, 768, 768, 768, 768, 768, 768, 2304, 768};
  for (int i = 0; i < 14; i++) WT[i] = (bf16_t*)alloc((size_t)wins[i] * wout[i] * 2);
  float*  q1  = (float*)alloc(BNC * 4);
  float*  q2  = (float*)alloc(BNC * 4);
  bf16_t* q2b = (bf16_t*)alloc(BNC * 2);
  const size_t arena = off;

  // dynamic chunk sizes: keep watermark <= ws_size (with ~4MB slack for alignment)
  const size_t slack = 4u << 20;
  size_t rem = (ws_size > arena + slack) ? ws_size - arena - slack : 0;
  // stage 2: fixed 3*BNC*2 shared + g2 * 5 * (3*NC*2)
  int g2 = 4;
  while (g2 > 1 && 3 * BNC * 2 + (size_t)g2 * 5 * (3 * NC * 2) > rem) g2 >>= 1;
  // stage 3: fixed 3*(2*BNC)*2 shared + h3 * 5 * (2*NC*2)
  int h3 = 8;
  while (h3 > 1 && 3 * (2 * BNC) * 2 + (size_t)h3 * 5 * (2 * NC * 2) > rem) h3 >>= 1;

  float* dof = (float*)d_out;                  // [0,2BNC) images, [2BNC,3BNC) change
  float* chg = dof + 2 * BNC;

  for (int i = 0; i < 14; i++) {
    dim3 g(wins[i] / 32, wout[i] / 32);
    k_wt<<<g, 256, 0, stream>>>((const float*)d_in[widx[i]], WT[i], wins[i], wout[i]);
  }

  // ================= stage 1: self-attention (full batch) =================
  off = arena;
  bf16_t* qpe_b = (bf16_t*)alloc(BNC * 2);
  bf16_t* q0_b  = (bf16_t*)alloc(BNC * 2);
  bf16_t* Qh    = (bf16_t*)alloc(BNC * 2);
  bf16_t* Kh    = (bf16_t*)alloc(BNC * 2);
  bf16_t* Vh    = (bf16_t*)alloc(BNC * 2);
  bf16_t* vT1   = (bf16_t*)alloc(BNC * 2);
  bf16_t* attC  = (bf16_t*)alloc(BNC * 2);
  float*  a1    = dof;

  k_prep1<<<dim3((int)(BNC / 4 / 256)), 256, 0, stream>>>(
      (const float4*)queries, (const float4*)change, (const float4*)pe, qpe_b, q0_b, (int)(BNC / 4));
  gemm(stream, qpe_b, WT[0], bq1, Qh, 1, 0, B * N, C, C, C, C, C, scale);
  gemm(stream, qpe_b, WT[1], bk1, Kh, 1, 0, B * N, C, C, C, C, C);
  gemm(stream, q0_b,  WT[2], bv1, Vh, 1, 0, B * N, C, C, C, C, C);
  k_vt<<<dim3(N / 32, 4, B * Hh), 256, 0, stream>>>(Vh, vT1, N, C, Hh);
  k_flash<<<dim3(N / 128, B * Hh), 256, 0, stream>>>(Qh, Kh, vT1, attC, N, C, Hh, (long)NC, (long)NC);
  gemm(stream, attC, WT[3], bo1, a1, 0, 0, B * N, C, C, C, C, C);
  k_ln<<<dim3(B * N), 256, 0, stream>>>(queries, change, a1, ln1w, ln1b, q1, (bf16_t*)nullptr);

  // ================= stage 2: cross-attn change -> [A,B,change] =================
  off = arena;
  bf16_t* qf    = (bf16_t*)alloc(BNC * 2);
  bf16_t* Q2h   = (bf16_t*)alloc(BNC * 2);
  bf16_t* attC2 = (bf16_t*)alloc(BNC * 2);
  bf16_t* k2in  = (bf16_t*)alloc((size_t)g2 * 3 * NC * 2);
  bf16_t* v2in  = (bf16_t*)alloc((size_t)g2 * 3 * NC * 2);
  bf16_t* K2h   = (bf16_t*)alloc((size_t)g2 * 3 * NC * 2);
  bf16_t* V2h   = (bf16_t*)alloc((size_t)g2 * 3 * NC * 2);
  bf16_t* vT2   = (bf16_t*)alloc((size_t)g2 * 3 * NC * 2);
  float*  a2    = dof;

  k_addpe<<<dim3((int)(BNC / 4 / 256)), 256, 0, stream>>>(q1, pe, fc, qf);
  gemm(stream, qf, WT[4], bq2, Q2h, 1, 0, B * N, C, C, C, C, C, scale);
  for (int b0 = 0; b0 < B; b0 += g2) {
    const int Nk = 3 * N;
    for (int bl = 0; bl < g2; ++bl)
      k_build2b<<<dim3((int)(3 * NC / 4 / 256)), 256, 0, stream>>>(
          q1, imA, imB, pe, fa, fb, fc, k2in + (size_t)bl * 3 * NC, v2in + (size_t)bl * 3 * NC, b0 + bl);
    gemm(stream, k2in, WT[5], bk2, K2h, 1, 0, g2 * Nk, C, C, C, C, C);
    gemm(stream, v2in, WT[6], bv2, V2h, 1, 0, g2 * Nk, C, C, C, C, C);
    k_vt<<<dim3(Nk / 32, 4, g2 * Hh), 256, 0, stream>>>(V2h, vT2, Nk, C, Hh);
    k_flash<<<dim3(N / 128, g2 * Hh), 256, 0, stream>>>(Q2h + (size_t)b0 * NC, K2h, vT2,
                                                        attC2 + (size_t)b0 * NC, Nk, C, Hh,
                                                        (long)NC, (long)(3 * NC));
  }
  gemm(stream, attC2, WT[7], bo2, a2, 0, 0, B * N, C, C, C, C, C);
  k_ln<<<dim3(B * N), 256, 0, stream>>>(q1, (const float*)nullptr, a2, ln2w, ln2b, q2, q2b);

  // ================= MLP =================
  off = arena;
  bf16_t* h1 = (bf16_t*)alloc((size_t)B * N * MLPD * 2);
  float*  a3 = dof;
  gemm(stream, q2b, WT[12], mb1, h1, 1, 1, B * N, MLPD, C, C, C, MLPD);
  gemm(stream, h1, WT[13], mb2, a3, 0, 0, B * N, C, MLPD, MLPD, MLPD, C);
  k_ln<<<dim3(B * N), 256, 0, stream>>>(q2, (const float*)nullptr, a3, ln3w, ln3b, chg, (bf16_t*)nullptr);

  // ================= stage 3: [A;B] -> [image;change] =================
  off = arena;
  bf16_t* qq    = (bf16_t*)alloc(2 * BNC * 2);
  bf16_t* Q3h   = (bf16_t*)alloc(2 * BNC * 2);
  bf16_t* attC3 = (bf16_t*)alloc(2 * BNC * 2);
  bf16_t* k3in  = (bf16_t*)alloc((size_t)h3 * 2 * NC * 2);
  bf16_t* v3in  = (bf16_t*)alloc((size_t)h3 * 2 * NC * 2);
  bf16_t* K3h   = (bf16_t*)alloc((size_t)h3 * 2 * NC * 2);
  bf16_t* V3h   = (bf16_t*)alloc((size_t)h3 * 2 * NC * 2);
  bf16_t* vT3   = (bf16_t*)alloc((size_t)h3 * 2 * NC * 2);

  k_buildqq<<<dim3((int)(2 * BNC / 4 / 256)), 256, 0, stream>>>(imA, imB, pe, fa, fb, qq);
  gemm(stream, qq, WT[8], bq3, Q3h, 1, 0, 2 * B * N, C, C, C, C, C, scale);
  for (int bb0 = 0; bb0 < 2 * B; bb0 += h3) {
    const int Nk = 2 * N;
    for (int bl = 0; bl < h3; ++bl)
      k_build3b<<<dim3((int)(2 * NC / 4 / 256)), 256, 0, stream>>>(
          chg, imA, imB, pe, fa, fb, fc, k3in + (size_t)bl * 2 * NC, v3in + (size_t)bl * 2 * NC, bb0 + bl);
    gemm(stream, k3in, WT[9],  bk3, K3h, 1, 0, h3 * Nk, C, C, C, C, C);
    gemm(stream, v3in, WT[10], bv3, V3h, 1, 0, h3 * Nk, C, C, C, C, C);
    k_vt<<<dim3(Nk / 32, 4, h3 * Hh), 256, 0, stream>>>(V3h, vT3, Nk, C, Hh);
    k_flash<<<dim3(N / 128, h3 * Hh), 256, 0, stream>>>(Q3h + (size_t)bb0 * NC, K3h, vT3,
                                                        attC3 + (size_t)bb0 * NC, Nk, C, Hh,
                                                        (long)NC, (long)(2 * NC));
  }
  gemm(stream, attC3, WT[11], bo3, dof, 0, 0, 2 * B * N, C, C, C, C, C);
  k_out3f<<<dim3((int)(2 * BNC / 4 / 256)), 256, 0, stream>>>(imA, imB, pe, fa, fb, dof);
}